// Round 6
// baseline (4845.817 us; speedup 1.0000x reference)
//
#include <hip/hip_runtime.h>

#define CDIM 64
#define COARSE_SHIFT 10          // 1024 rows per coarse bucket
#define FINE_SHIFT 6             // 64 rows per fine bucket
#define CHUNK 8192
#define MAXB 256                 // >= max coarse buckets (200000>>10 = 196)

// ---------------- init: residual slots of d_out ----------------
__global__ void init_kernel(const float4* __restrict__ user_emb,
                            const float4* __restrict__ ent_emb,
                            float4* __restrict__ outUserRes,
                            float4* __restrict__ outNodeRes,
                            long nuC4, long neC4) {
    long i = (long)blockIdx.x * blockDim.x + threadIdx.x;
    if (i < nuC4) { float4 v = user_emb[i]; outUserRes[i] = v; outNodeRes[i] = v; }
    if (i < neC4) { outNodeRes[nuC4 + i] = ent_emb[i]; }
}

// ---------------- coarse histogram (LDS-staged) ----------------
__global__ void hist_coarse(const int* __restrict__ dst, int n,
                            int* __restrict__ cnt, int Bc) {
    __shared__ int h[MAXB];
    for (int i = threadIdx.x; i < MAXB; i += blockDim.x) h[i] = 0;
    __syncthreads();
    int stride = gridDim.x * blockDim.x;
    for (int e = blockIdx.x * blockDim.x + threadIdx.x; e < n; e += stride)
        atomicAdd(&h[dst[e] >> COARSE_SHIFT], 1);
    __syncthreads();
    for (int b = threadIdx.x; b < Bc; b += blockDim.x)
        if (h[b]) atomicAdd(&cnt[b], h[b]);
}

// ---------------- small exclusive scan (single WG) ----------------
__global__ void scan_small(const int* __restrict__ cnt, int* __restrict__ start,
                           int* __restrict__ cursor, int n) {
    __shared__ int tmp[256];
    __shared__ int carryS;
    if (threadIdx.x == 0) carryS = 0;
    __syncthreads();
    for (int base = 0; base < n; base += 256) {
        int i = base + threadIdx.x;
        int v = (i < n) ? cnt[i] : 0;
        tmp[threadIdx.x] = v;
        __syncthreads();
        for (int off = 1; off < 256; off <<= 1) {
            int t = (threadIdx.x >= off) ? tmp[threadIdx.x - off] : 0;
            __syncthreads();
            tmp[threadIdx.x] += t;
            __syncthreads();
        }
        int excl = carryS + tmp[threadIdx.x] - v;
        if (i < n) { start[i] = excl; cursor[i] = excl; }
        __syncthreads();
        if (threadIdx.x == 255) carryS += tmp[255];
        __syncthreads();
    }
    if (threadIdx.x == 0) start[n] = carryS;
}

// ---------------- coarse binning, LDS-staged segment writes ----------------
// key = (dst&1023)<<22 | typ<<18 | src   (src<2^18, typ<16)
__global__ void bin_pairs(const int* __restrict__ dst, const int* __restrict__ src,
                          const int* __restrict__ typ, int typeBias, int n,
                          int* __restrict__ cursor, int* __restrict__ stage) {
    __shared__ int h[MAXB];
    __shared__ int base[MAXB];
    int cs = blockIdx.x * CHUNK;
    int ce = min(cs + CHUNK, n);
    for (int i = threadIdx.x; i < MAXB; i += blockDim.x) h[i] = 0;
    __syncthreads();
    for (int e = cs + threadIdx.x; e < ce; e += blockDim.x)
        atomicAdd(&h[dst[e] >> COARSE_SHIFT], 1);
    __syncthreads();
    for (int b = threadIdx.x; b < MAXB; b += blockDim.x) {
        int c = h[b];
        base[b] = c ? atomicAdd(&cursor[b], c) : 0;
        h[b] = 0;
    }
    __syncthreads();
    for (int e = cs + threadIdx.x; e < ce; e += blockDim.x) {
        int d = dst[e];
        int b = d >> COARSE_SHIFT;
        int off = atomicAdd(&h[b], 1);
        stage[base[b] + off] = ((d & 1023) << 22) | ((typ[e] + typeBias) << 18) | src[e];
    }
}

// user variant: key = (dst&1023)<<22 | col (col<2^17), parallel val array
__global__ void bin_user(const int* __restrict__ row, const int* __restrict__ col,
                         const float* __restrict__ val, int n,
                         int* __restrict__ cursor,
                         int* __restrict__ stage, float* __restrict__ stageVal) {
    __shared__ int h[MAXB];
    __shared__ int base[MAXB];
    int cs = blockIdx.x * CHUNK;
    int ce = min(cs + CHUNK, n);
    for (int i = threadIdx.x; i < MAXB; i += blockDim.x) h[i] = 0;
    __syncthreads();
    for (int e = cs + threadIdx.x; e < ce; e += blockDim.x)
        atomicAdd(&h[row[e] >> COARSE_SHIFT], 1);
    __syncthreads();
    for (int b = threadIdx.x; b < MAXB; b += blockDim.x) {
        int c = h[b];
        base[b] = c ? atomicAdd(&cursor[b], c) : 0;
        h[b] = 0;
    }
    __syncthreads();
    for (int e = cs + threadIdx.x; e < ce; e += blockDim.x) {
        int d = row[e];
        int b = d >> COARSE_SHIFT;
        int off = atomicAdd(&h[b], 1);
        int pos = base[b] + off;
        stage[pos] = ((d & 1023) << 22) | col[e];
        stageVal[pos] = val[e];
    }
}

// ---------------- sub-bin within coarse bucket (L2-resident window) ----------------
__global__ void subsort(const int* __restrict__ coarseStart,
                        const int* __restrict__ stage, const float* __restrict__ stageVal,
                        int* __restrict__ bin, float* __restrict__ binVal,
                        int* __restrict__ fineOff, int Bc, int Bf) {
    __shared__ int fh[16], fbase[16];
    int c = blockIdx.x;
    int s = coarseStart[c], e = coarseStart[c + 1];
    if (threadIdx.x < 16) fh[threadIdx.x] = 0;
    __syncthreads();
    for (int j = s + threadIdx.x; j < e; j += blockDim.x)
        atomicAdd(&fh[(stage[j] >> 28) & 15], 1);
    __syncthreads();
    if (threadIdx.x == 0) {
        int run = 0;
        for (int k = 0; k < 16; ++k) { fbase[k] = run; run += fh[k]; }
    }
    __syncthreads();
    if (threadIdx.x < 16) {
        int fb = (c << (COARSE_SHIFT - FINE_SHIFT)) + threadIdx.x;
        if (fb < Bf) fineOff[fb] = s + fbase[threadIdx.x];
        fh[threadIdx.x] = 0;
    }
    if (threadIdx.x == 0 && c == Bc - 1) fineOff[Bf] = e;
    __syncthreads();
    for (int j = s + threadIdx.x; j < e; j += blockDim.x) {
        int k = stage[j];
        int sub = (k >> 28) & 15;
        int pos = s + fbase[sub] + atomicAdd(&fh[sub], 1);
        bin[pos] = k;
        if (binVal) binVal[pos] = stageVal[j];
    }
}

// ---------------- per-hop fused scatter kernels ----------------
// One WG per 64-row fine bucket; quarter-wave (16 lanes x float4) per edge;
// LDS fp32 atomic accumulation; coalesced normalize+write epilogue.

__global__ void __launch_bounds__(256)
ent_hop(const float* __restrict__ entCur, const float4* __restrict__ weight,
        const int* __restrict__ fineOff, const int* __restrict__ bin,
        float* __restrict__ entNew, float* __restrict__ entNorm, int NE) {
    __shared__ float acc[64 * CDIM];
    __shared__ int cnt[64];
    __shared__ float4 wlds[15 * 16];
    for (int i = threadIdx.x; i < 15 * 16; i += blockDim.x) wlds[i] = weight[i];
    float4* a4 = (float4*)acc;
    for (int i = threadIdx.x; i < 64 * 16; i += blockDim.x) a4[i] = make_float4(0,0,0,0);
    if (threadIdx.x < 64) cnt[threadIdx.x] = 0;
    __syncthreads();
    int fb = blockIdx.x;
    int js = fineOff[fb], je = fineOff[fb + 1];
    int Q = threadIdx.x >> 4;
    int l = threadIdx.x & 15;
    for (int j = js + Q; j < je; j += 16) {
        int k = bin[j];
        int row = (k >> 22) & 63;
        int r = (k >> 18) & 15;
        int src = k & 0x3FFFF;
        float4 v = ((const float4*)(entCur + (long)src * CDIM))[l];
        float4 w = wlds[r * 16 + l];
        float* a = acc + row * CDIM + l * 4;
        atomicAdd(a + 0, v.x * w.x);
        atomicAdd(a + 1, v.y * w.y);
        atomicAdd(a + 2, v.z * w.z);
        atomicAdd(a + 3, v.w * w.w);
        if (l == 0) atomicAdd(&cnt[row], 1);
    }
    __syncthreads();
    for (int row = Q; row < 64; row += 16) {
        int gr = (fb << FINE_SHIFT) + row;
        if (gr >= NE) break;
        float4 a = a4[row * 16 + l];
        float inv = 1.0f / fmaxf((float)cnt[row], 1.0f);
        float4 m = make_float4(a.x*inv, a.y*inv, a.z*inv, a.w*inv);
        float q2 = m.x*m.x + m.y*m.y + m.z*m.z + m.w*m.w;
        #pragma unroll
        for (int off = 1; off < 16; off <<= 1) q2 += __shfl_xor(q2, off, 64);
        float n = fmaxf(sqrtf(q2), 1e-12f);
        float rn = 1.0f / n;
        ((float4*)(entNew + (long)gr * CDIM))[l] =
            make_float4(m.x*rn, m.y*rn, m.z*rn, m.w*rn);
        if (l == 0) entNorm[gr] = n;
    }
}

__global__ void __launch_bounds__(256)
node_hop(const float* __restrict__ nodeUold, const float* __restrict__ entCur,
         const float4* __restrict__ extraW,
         const int* __restrict__ fineOff, const int* __restrict__ bin,
         float* __restrict__ nodeUnew, float* __restrict__ resOut,
         int NN, int NU) {
    __shared__ float acc[64 * CDIM];
    __shared__ int cnt[64];
    __shared__ float4 wlds[16 * 16];
    for (int i = threadIdx.x; i < 16 * 16; i += blockDim.x) wlds[i] = extraW[i];
    float4* a4 = (float4*)acc;
    for (int i = threadIdx.x; i < 64 * 16; i += blockDim.x) a4[i] = make_float4(0,0,0,0);
    if (threadIdx.x < 64) cnt[threadIdx.x] = 0;
    __syncthreads();
    int fb = blockIdx.x;
    int js = fineOff[fb], je = fineOff[fb + 1];
    int Q = threadIdx.x >> 4;
    int l = threadIdx.x & 15;
    for (int j = js + Q; j < je; j += 16) {
        int k = bin[j];
        int row = (k >> 22) & 63;
        int r = (k >> 18) & 15;
        int src = k & 0x3FFFF;
        const float* bp = (src < NU) ? (nodeUold + (long)src * CDIM)
                                     : (entCur + (long)(src - NU) * CDIM);
        float4 v = ((const float4*)bp)[l];
        float4 w = wlds[r * 16 + l];
        float* a = acc + row * CDIM + l * 4;
        atomicAdd(a + 0, v.x * w.x);
        atomicAdd(a + 1, v.y * w.y);
        atomicAdd(a + 2, v.z * w.z);
        atomicAdd(a + 3, v.w * w.w);
        if (l == 0) atomicAdd(&cnt[row], 1);
    }
    __syncthreads();
    for (int row = Q; row < 64; row += 16) {
        int gr = (fb << FINE_SHIFT) + row;
        if (gr >= NN) break;
        float4 a = a4[row * 16 + l];
        float inv = 1.0f / fmaxf((float)cnt[row], 1.0f);
        float4 m = make_float4(a.x*inv, a.y*inv, a.z*inv, a.w*inv);
        float q2 = m.x*m.x + m.y*m.y + m.z*m.z + m.w*m.w;
        #pragma unroll
        for (int off = 1; off < 16; off <<= 1) q2 += __shfl_xor(q2, off, 64);
        float rn = 1.0f / fmaxf(sqrtf(q2), 1e-12f);
        float4 o = make_float4(m.x*rn, m.y*rn, m.z*rn, m.w*rn);
        float4* resRow = (float4*)(resOut + (long)gr * CDIM);
        float4 rv = resRow[l];
        resRow[l] = make_float4(rv.x + o.x, rv.y + o.y, rv.z + o.z, rv.w + o.w);
        if (gr < NU) ((float4*)(nodeUnew + (long)gr * CDIM))[l] = o;
    }
}

__global__ void __launch_bounds__(256)
user_hop(const float* __restrict__ entNew, const float* __restrict__ entNorm,
         const int* __restrict__ fineOff, const int* __restrict__ bin,
         const float* __restrict__ binVal,
         float* __restrict__ userRes, int NU) {
    __shared__ float acc[64 * CDIM];
    float4* a4 = (float4*)acc;
    for (int i = threadIdx.x; i < 64 * 16; i += blockDim.x) a4[i] = make_float4(0,0,0,0);
    __syncthreads();
    int fb = blockIdx.x;
    int js = fineOff[fb], je = fineOff[fb + 1];
    int Q = threadIdx.x >> 4;
    int l = threadIdx.x & 15;
    for (int j = js + Q; j < je; j += 16) {
        int k = bin[j];
        int row = (k >> 22) & 63;
        int col = k & 0x1FFFF;
        float f = entNorm[col] * binVal[j];        // reconstruct pre-norm mean scale
        float4 v = ((const float4*)(entNew + (long)col * CDIM))[l];
        float* a = acc + row * CDIM + l * 4;
        atomicAdd(a + 0, v.x * f);
        atomicAdd(a + 1, v.y * f);
        atomicAdd(a + 2, v.z * f);
        atomicAdd(a + 3, v.w * f);
    }
    __syncthreads();
    for (int row = Q; row < 64; row += 16) {
        int gr = (fb << FINE_SHIFT) + row;
        if (gr >= NU) break;
        float4 a = a4[row * 16 + l];
        float q2 = a.x*a.x + a.y*a.y + a.z*a.z + a.w*a.w;
        #pragma unroll
        for (int off = 1; off < 16; off <<= 1) q2 += __shfl_xor(q2, off, 64);
        float rn = 1.0f / fmaxf(sqrtf(q2), 1e-12f);
        float4* resRow = (float4*)(userRes + (long)gr * CDIM);
        float4 rv = resRow[l];
        resRow[l] = make_float4(rv.x + a.x*rn, rv.y + a.y*rn,
                                rv.z + a.z*rn, rv.w + a.w*rn);
    }
}

__global__ void fill_debug(float* __restrict__ out, long n, float val) {
    long i = (long)blockIdx.x * blockDim.x + threadIdx.x;
    if (i < n) out[i] = val;
}

extern "C" void kernel_launch(void* const* d_in, const int* in_sizes, int n_in,
                              void* d_out, int out_size, void* d_ws, size_t ws_size,
                              hipStream_t stream) {
    const float* user_emb = (const float*)d_in[0];
    const float* ent_emb  = (const float*)d_in[1];
    const float* weight   = (const float*)d_in[2];
    const float* extraW   = (const float*)d_in[3];
    const float* imVal    = (const float*)d_in[4];
    const int*   eidx     = (const int*)d_in[5];
    const int*   etype    = (const int*)d_in[6];
    const int*   xidx     = (const int*)d_in[7];
    const int*   xtype    = (const int*)d_in[8];
    const int*   imRow    = (const int*)d_in[9];
    const int*   imCol    = (const int*)d_in[10];

    const int NU  = in_sizes[0] / CDIM;
    const int NE  = in_sizes[1] / CDIM;
    const int NN  = NU + NE;
    const int E   = in_sizes[5] / 2;
    const int E2  = in_sizes[7] / 2;
    const int NNZ = in_sizes[4];
    const long nuC = (long)NU * CDIM, neC = (long)NE * CDIM, nnC = (long)NN * CDIM;

    const int BcE = (NE + 1023) >> 10, BcN = (NN + 1023) >> 10, BcU = (NU + 1023) >> 10;
    const int BfE = (NE + 63) >> 6,    BfN = (NN + 63) >> 6,    BfU = (NU + 63) >> 6;

    float* out = (float*)d_out;
    float* outUserRes = out;            // [0 : nuC]
    float* entOut     = out + nuC;      // [nuC : nnC] ping-pong; final hop lands here
    float* outNodeRes = out + nnC;      // [nnC : 2nnC]

    // ---- workspace layout ----
    size_t required = (size_t)(neC + 2 * nuC) * 4          // entA, nodeU_A, nodeU_B
                    + (size_t)NE * 4                        // entNorm
                    + (size_t)(E + E2 + NNZ) * 4 * 2        // stage + bin keys
                    + (size_t)NNZ * 4 * 2                   // stageVal + binVal
                    + (size_t)(3 * MAXB) * 4                // coarse counts
                    + (size_t)(3 * (MAXB + 1)) * 4          // coarse starts
                    + (size_t)(3 * MAXB) * 4                // cursors
                    + (size_t)(BfE + BfN + BfU + 3) * 4;    // fine offsets
    if (ws_size < required) {
        long total = 2 * nnC;
        fill_debug<<<(total + 255) / 256, 256, 0, stream>>>(out, total, (float)(ws_size >> 20));
        return;
    }

    char* w = (char*)d_ws;
    float* entA     = (float*)w; w += (size_t)neC * 4;
    float* nodeU_A  = (float*)w; w += (size_t)nuC * 4;
    float* nodeU_B  = (float*)w; w += (size_t)nuC * 4;
    float* entNorm  = (float*)w; w += (size_t)NE * 4;
    int* stageEnt   = (int*)w;   w += (size_t)E * 4;
    int* stageNode  = (int*)w;   w += (size_t)E2 * 4;
    int* stageU     = (int*)w;   w += (size_t)NNZ * 4;
    float* stageUv  = (float*)w; w += (size_t)NNZ * 4;
    int* binEnt     = (int*)w;   w += (size_t)E * 4;
    int* binNode    = (int*)w;   w += (size_t)E2 * 4;
    int* binU       = (int*)w;   w += (size_t)NNZ * 4;
    float* binUv    = (float*)w; w += (size_t)NNZ * 4;
    int* cntC       = (int*)w;   w += (size_t)(3 * MAXB) * 4;      // ent|node|user
    int* startE     = (int*)w;   w += (size_t)(MAXB + 1) * 4;
    int* startN     = (int*)w;   w += (size_t)(MAXB + 1) * 4;
    int* startU     = (int*)w;   w += (size_t)(MAXB + 1) * 4;
    int* curE       = (int*)w;   w += (size_t)MAXB * 4;
    int* curN       = (int*)w;   w += (size_t)MAXB * 4;
    int* curU       = (int*)w;   w += (size_t)MAXB * 4;
    int* foffE      = (int*)w;   w += (size_t)(BfE + 1) * 4;
    int* foffN      = (int*)w;   w += (size_t)(BfN + 1) * 4;
    int* foffU      = (int*)w;   w += (size_t)(BfU + 1) * 4;

    const int* head = eidx;  const int* tail = eidx + E;
    const int* eh   = xidx;  const int* et   = xidx + E2;

    hipMemsetAsync(cntC, 0, (size_t)(3 * MAXB) * 4, stream);

    long initN4 = (nuC > neC ? nuC : neC) / 4;
    init_kernel<<<(initN4 + 255) / 256, 256, 0, stream>>>(
        (const float4*)user_emb, (const float4*)ent_emb,
        (float4*)outUserRes, (float4*)outNodeRes, nuC / 4, neC / 4);

    // ---- build: hist -> scan -> coarse bin -> sub-bin ----
    hist_coarse<<<256, 256, 0, stream>>>(head,  E,   cntC,            BcE);
    hist_coarse<<<256, 256, 0, stream>>>(eh,    E2,  cntC + MAXB,     BcN);
    hist_coarse<<<256, 256, 0, stream>>>(imRow, NNZ, cntC + 2 * MAXB, BcU);

    scan_small<<<1, 256, 0, stream>>>(cntC,            startE, curE, BcE);
    scan_small<<<1, 256, 0, stream>>>(cntC + MAXB,     startN, curN, BcN);
    scan_small<<<1, 256, 0, stream>>>(cntC + 2 * MAXB, startU, curU, BcU);

    bin_pairs<<<(E  + CHUNK - 1) / CHUNK, 256, 0, stream>>>(head, tail, etype, -1, E,  curE, stageEnt);
    bin_pairs<<<(E2 + CHUNK - 1) / CHUNK, 256, 0, stream>>>(eh,   et,   xtype,  0, E2, curN, stageNode);
    bin_user <<<(NNZ + CHUNK - 1) / CHUNK, 256, 0, stream>>>(imRow, imCol, imVal, NNZ, curU, stageU, stageUv);

    subsort<<<BcE, 256, 0, stream>>>(startE, stageEnt,  nullptr, binEnt,  nullptr, foffE, BcE, BfE);
    subsort<<<BcN, 256, 0, stream>>>(startN, stageNode, nullptr, binNode, nullptr, foffN, BcN, BfN);
    subsort<<<BcU, 256, 0, stream>>>(startU, stageU,    stageUv, binU,    binUv,   foffU, BcU, BfU);

    // ---- 3 hops ----
    const float* entCurP  = ent_emb;   float* entNewP  = entOut;
    const float* nodeOldP = user_emb;  float* nodeNewP = nodeU_A;

    for (int hop = 0; hop < 3; ++hop) {
        ent_hop<<<BfE, 256, 0, stream>>>(
            entCurP, (const float4*)weight, foffE, binEnt, entNewP, entNorm, NE);
        node_hop<<<BfN, 256, 0, stream>>>(
            nodeOldP, entCurP, (const float4*)extraW, foffN, binNode,
            nodeNewP, outNodeRes, NN, NU);
        user_hop<<<BfU, 256, 0, stream>>>(
            entNewP, entNorm, foffU, binU, binUv, outUserRes, NU);

        if (hop == 0) {
            entCurP = entOut;  entNewP = entA;
            nodeOldP = nodeU_A; nodeNewP = nodeU_B;
        } else if (hop == 1) {
            entCurP = entA;    entNewP = entOut;
            nodeOldP = nodeU_B; nodeNewP = nodeU_A;
        }
    }
}

// Round 7
// 1105.483 us; speedup vs baseline: 4.3834x; 4.3834x over previous
//
#include <hip/hip_runtime.h>

#define CDIM 64
#define COARSE_SHIFT 10          // 1024 rows per coarse bucket
#define CHUNK 8192
#define MAXB 256                 // >= max coarse buckets (200000>>10 = 196)

// ---------------- init: residual slots of d_out ----------------
__global__ void init_kernel(const float4* __restrict__ user_emb,
                            const float4* __restrict__ ent_emb,
                            float4* __restrict__ outUserRes,
                            float4* __restrict__ outNodeRes,
                            long nuC4, long neC4) {
    long i = (long)blockIdx.x * blockDim.x + threadIdx.x;
    if (i < nuC4) { float4 v = user_emb[i]; outUserRes[i] = v; outNodeRes[i] = v; }
    if (i < neC4) { outNodeRes[nuC4 + i] = ent_emb[i]; }
}

// ---------------- coarse histogram (LDS-staged) ----------------
__global__ void hist_coarse(const int* __restrict__ dst, int n,
                            int* __restrict__ cnt, int Bc) {
    __shared__ int h[MAXB];
    for (int i = threadIdx.x; i < MAXB; i += blockDim.x) h[i] = 0;
    __syncthreads();
    int stride = gridDim.x * blockDim.x;
    for (int e = blockIdx.x * blockDim.x + threadIdx.x; e < n; e += stride)
        atomicAdd(&h[dst[e] >> COARSE_SHIFT], 1);
    __syncthreads();
    for (int b = threadIdx.x; b < Bc; b += blockDim.x)
        if (h[b]) atomicAdd(&cnt[b], h[b]);
}

// ---------------- small exclusive scan (single WG, n<=256) ----------------
__global__ void scan_small(const int* __restrict__ cnt, int* __restrict__ start,
                           int* __restrict__ cursor, int n) {
    __shared__ int tmp[256];
    int x = threadIdx.x;
    int v = (x < n) ? cnt[x] : 0;
    tmp[x] = v; __syncthreads();
    for (int off = 1; off < 256; off <<= 1) {
        int t = (x >= off) ? tmp[x - off] : 0;
        __syncthreads();
        tmp[x] += t;
        __syncthreads();
    }
    if (x < n) { start[x] = tmp[x] - v; cursor[x] = tmp[x] - v; }
    if (x == n - 1) start[n] = tmp[x];
}

// ---------------- coarse binning, LDS-staged segment writes ----------------
// key = rowlocal<<22 | typ<<18 | src   (rowlocal<1024, typ<16, src<2^18)
__global__ void bin_pairs(const int* __restrict__ dst, const int* __restrict__ src,
                          const int* __restrict__ typ, int typeBias, int n,
                          int* __restrict__ cursor, int* __restrict__ stage) {
    __shared__ int h[MAXB];
    __shared__ int base[MAXB];
    int cs = blockIdx.x * CHUNK;
    int ce = min(cs + CHUNK, n);
    for (int i = threadIdx.x; i < MAXB; i += blockDim.x) h[i] = 0;
    __syncthreads();
    for (int e = cs + threadIdx.x; e < ce; e += blockDim.x)
        atomicAdd(&h[dst[e] >> COARSE_SHIFT], 1);
    __syncthreads();
    for (int b = threadIdx.x; b < MAXB; b += blockDim.x) {
        int c = h[b];
        base[b] = c ? atomicAdd(&cursor[b], c) : 0;
        h[b] = 0;
    }
    __syncthreads();
    for (int e = cs + threadIdx.x; e < ce; e += blockDim.x) {
        int d = dst[e];
        int b = d >> COARSE_SHIFT;
        int off = atomicAdd(&h[b], 1);
        stage[base[b] + off] = ((d & 1023) << 22) | ((typ[e] + typeBias) << 18) | src[e];
    }
}

// user variant: key = rowlocal<<22 | col (col<2^22), parallel val array
__global__ void bin_user(const int* __restrict__ row, const int* __restrict__ col,
                         const float* __restrict__ val, int n,
                         int* __restrict__ cursor,
                         int* __restrict__ stage, float* __restrict__ stageVal) {
    __shared__ int h[MAXB];
    __shared__ int base[MAXB];
    int cs = blockIdx.x * CHUNK;
    int ce = min(cs + CHUNK, n);
    for (int i = threadIdx.x; i < MAXB; i += blockDim.x) h[i] = 0;
    __syncthreads();
    for (int e = cs + threadIdx.x; e < ce; e += blockDim.x)
        atomicAdd(&h[row[e] >> COARSE_SHIFT], 1);
    __syncthreads();
    for (int b = threadIdx.x; b < MAXB; b += blockDim.x) {
        int c = h[b];
        base[b] = c ? atomicAdd(&cursor[b], c) : 0;
        h[b] = 0;
    }
    __syncthreads();
    for (int e = cs + threadIdx.x; e < ce; e += blockDim.x) {
        int d = row[e];
        int b = d >> COARSE_SHIFT;
        int off = atomicAdd(&h[b], 1);
        int pos = base[b] + off;
        stage[pos] = ((d & 1023) << 22) | col[e];
        stageVal[pos] = val[e];
    }
}

// ---------------- full per-row sort within coarse bucket (L2-resident) ----------------
// Emits row-sorted keys (bin) and global CSR rowStart[N+1].
__global__ void __launch_bounds__(256)
subsort(const int* __restrict__ coarseStart,
        const int* __restrict__ stage, const float* __restrict__ stageVal,
        int* __restrict__ bin, float* __restrict__ binVal,
        int* __restrict__ rowStart, int Bc, int N, int total) {
    __shared__ int h[1024];
    __shared__ int base[1024];
    __shared__ int sarr[256];
    int c = blockIdx.x;
    int s = coarseStart[c], e = coarseStart[c + 1];
    for (int i = threadIdx.x; i < 1024; i += 256) h[i] = 0;
    __syncthreads();
    for (int j = s + threadIdx.x; j < e; j += 256)
        atomicAdd(&h[(stage[j] >> 22) & 1023], 1);
    __syncthreads();
    int t = threadIdx.x;
    int l0 = h[4*t], l1 = h[4*t+1], l2 = h[4*t+2], l3 = h[4*t+3];
    int lsum = l0 + l1 + l2 + l3;
    sarr[t] = lsum;
    __syncthreads();
    for (int off = 1; off < 256; off <<= 1) {
        int v = (t >= off) ? sarr[t - off] : 0;
        __syncthreads();
        sarr[t] += v;
        __syncthreads();
    }
    int excl = sarr[t] - lsum;
    base[4*t] = excl; base[4*t+1] = excl + l0;
    base[4*t+2] = excl + l0 + l1; base[4*t+3] = excl + l0 + l1 + l2;
    __syncthreads();
    int rowBase = c << COARSE_SHIFT;
    for (int i = threadIdx.x; i < 1024; i += 256) {
        int gr = rowBase + i;
        if (gr < N) rowStart[gr] = s + base[i];
    }
    if (threadIdx.x == 0 && c == Bc - 1) rowStart[N] = total;
    for (int i = threadIdx.x; i < 1024; i += 256) h[i] = 0;
    __syncthreads();
    for (int j = s + threadIdx.x; j < e; j += 256) {
        int k = stage[j];
        int r = (k >> 22) & 1023;
        int pos = s + base[r] + atomicAdd(&h[r], 1);
        bin[pos] = k;
        if (binVal) binVal[pos] = stageVal[j];
    }
}

// ---------------- gathers (round-5 structure, new packing) ----------------
// One wave per dest row. lane = 16*q + l: q = edge slot (4 in flight), l = float4 group.

__global__ void ent_gather(const float* __restrict__ entCur,
                           const float4* __restrict__ weight,
                           const int* __restrict__ rowStart,
                           const int* __restrict__ bin,
                           float* __restrict__ entNew,
                           float* __restrict__ entNorm,
                           int NE) {
    __shared__ float4 wlds[15 * 16];
    for (int i = threadIdx.x; i < 15 * 16; i += blockDim.x) wlds[i] = weight[i];
    __syncthreads();
    int row = blockIdx.x * (blockDim.x >> 6) + (threadIdx.x >> 6);
    int lane = threadIdx.x & 63;
    int q = lane >> 4, l = lane & 15;
    if (row >= NE) return;
    int start = rowStart[row], end = rowStart[row + 1];
    float4 acc = make_float4(0.f, 0.f, 0.f, 0.f);
    for (int j = start + q; j < end; j += 4) {
        int k = bin[j];
        int src = k & 0x3FFFF;
        int r = (k >> 18) & 15;
        float4 v = ((const float4*)(entCur + (long)src * CDIM))[l];
        float4 w = wlds[r * 16 + l];
        acc.x += v.x * w.x; acc.y += v.y * w.y;
        acc.z += v.z * w.z; acc.w += v.w * w.w;
    }
    #pragma unroll
    for (int off = 16; off < 64; off <<= 1) {
        acc.x += __shfl_xor(acc.x, off, 64);
        acc.y += __shfl_xor(acc.y, off, 64);
        acc.z += __shfl_xor(acc.z, off, 64);
        acc.w += __shfl_xor(acc.w, off, 64);
    }
    float inv = 1.0f / fmaxf((float)(end - start), 1.0f);
    float4 mean = make_float4(acc.x * inv, acc.y * inv, acc.z * inv, acc.w * inv);
    float q2 = mean.x * mean.x + mean.y * mean.y + mean.z * mean.z + mean.w * mean.w;
    #pragma unroll
    for (int off = 1; off < 16; off <<= 1) q2 += __shfl_xor(q2, off, 64);
    float n = fmaxf(sqrtf(q2), 1e-12f);
    float rn = 1.0f / n;
    if (q == 0) {
        ((float4*)(entNew + (long)row * CDIM))[l] =
            make_float4(mean.x * rn, mean.y * rn, mean.z * rn, mean.w * rn);
        if (l == 0) entNorm[row] = n;
    }
}

__global__ void node_gather(const float* __restrict__ nodeUold,
                            const float* __restrict__ entCur,
                            const float4* __restrict__ extraW,
                            const int* __restrict__ rowStart,
                            const int* __restrict__ bin,
                            float* __restrict__ nodeUnew,
                            float* __restrict__ resOut,
                            int NN, int NU) {
    __shared__ float4 wlds[16 * 16];
    for (int i = threadIdx.x; i < 16 * 16; i += blockDim.x) wlds[i] = extraW[i];
    __syncthreads();
    int row = blockIdx.x * (blockDim.x >> 6) + (threadIdx.x >> 6);
    int lane = threadIdx.x & 63;
    int q = lane >> 4, l = lane & 15;
    if (row >= NN) return;
    int start = rowStart[row], end = rowStart[row + 1];
    float4 acc = make_float4(0.f, 0.f, 0.f, 0.f);
    for (int j = start + q; j < end; j += 4) {
        int k = bin[j];
        int src = k & 0x3FFFF;
        int r = (k >> 18) & 15;
        const float* base = (src < NU) ? (nodeUold + (long)src * CDIM)
                                       : (entCur + (long)(src - NU) * CDIM);
        float4 v = ((const float4*)base)[l];
        float4 w = wlds[r * 16 + l];
        acc.x += v.x * w.x; acc.y += v.y * w.y;
        acc.z += v.z * w.z; acc.w += v.w * w.w;
    }
    #pragma unroll
    for (int off = 16; off < 64; off <<= 1) {
        acc.x += __shfl_xor(acc.x, off, 64);
        acc.y += __shfl_xor(acc.y, off, 64);
        acc.z += __shfl_xor(acc.z, off, 64);
        acc.w += __shfl_xor(acc.w, off, 64);
    }
    float inv = 1.0f / fmaxf((float)(end - start), 1.0f);
    float4 mean = make_float4(acc.x * inv, acc.y * inv, acc.z * inv, acc.w * inv);
    float q2 = mean.x * mean.x + mean.y * mean.y + mean.z * mean.z + mean.w * mean.w;
    #pragma unroll
    for (int off = 1; off < 16; off <<= 1) q2 += __shfl_xor(q2, off, 64);
    float rn = 1.0f / fmaxf(sqrtf(q2), 1e-12f);
    if (q == 0) {
        float4 o = make_float4(mean.x * rn, mean.y * rn, mean.z * rn, mean.w * rn);
        float4* resRow = (float4*)(resOut + (long)row * CDIM);
        float4 rv = resRow[l];
        resRow[l] = make_float4(rv.x + o.x, rv.y + o.y, rv.z + o.z, rv.w + o.w);
        if (row < NU) ((float4*)(nodeUnew + (long)row * CDIM))[l] = o;
    }
}

__global__ void user_gather(const float* __restrict__ entNew,
                            const float* __restrict__ entNorm,
                            const int* __restrict__ rowStart,
                            const int* __restrict__ bin,
                            const float* __restrict__ binVal,
                            float* __restrict__ userRes,
                            int NU) {
    int row = blockIdx.x * (blockDim.x >> 6) + (threadIdx.x >> 6);
    int lane = threadIdx.x & 63;
    int q = lane >> 4, l = lane & 15;
    if (row >= NU) return;
    int start = rowStart[row], end = rowStart[row + 1];
    float4 acc = make_float4(0.f, 0.f, 0.f, 0.f);
    for (int j = start + q; j < end; j += 4) {
        int col = bin[j] & 0x3FFFFF;
        float f = entNorm[col] * binVal[j];     // reconstruct pre-norm mean scale
        float4 v = ((const float4*)(entNew + (long)col * CDIM))[l];
        acc.x += v.x * f; acc.y += v.y * f;
        acc.z += v.z * f; acc.w += v.w * f;
    }
    #pragma unroll
    for (int off = 16; off < 64; off <<= 1) {
        acc.x += __shfl_xor(acc.x, off, 64);
        acc.y += __shfl_xor(acc.y, off, 64);
        acc.z += __shfl_xor(acc.z, off, 64);
        acc.w += __shfl_xor(acc.w, off, 64);
    }
    float q2 = acc.x * acc.x + acc.y * acc.y + acc.z * acc.z + acc.w * acc.w;
    #pragma unroll
    for (int off = 1; off < 16; off <<= 1) q2 += __shfl_xor(q2, off, 64);
    float rn = 1.0f / fmaxf(sqrtf(q2), 1e-12f);
    if (q == 0) {
        float4* resRow = (float4*)(userRes + (long)row * CDIM);
        float4 rv = resRow[l];
        resRow[l] = make_float4(rv.x + acc.x * rn, rv.y + acc.y * rn,
                                rv.z + acc.z * rn, rv.w + acc.w * rn);
    }
}

__global__ void fill_debug(float* __restrict__ out, long n, float val) {
    long i = (long)blockIdx.x * blockDim.x + threadIdx.x;
    if (i < n) out[i] = val;
}

extern "C" void kernel_launch(void* const* d_in, const int* in_sizes, int n_in,
                              void* d_out, int out_size, void* d_ws, size_t ws_size,
                              hipStream_t stream) {
    const float* user_emb = (const float*)d_in[0];
    const float* ent_emb  = (const float*)d_in[1];
    const float* weight   = (const float*)d_in[2];
    const float* extraW   = (const float*)d_in[3];
    const float* imVal    = (const float*)d_in[4];
    const int*   eidx     = (const int*)d_in[5];
    const int*   etype    = (const int*)d_in[6];
    const int*   xidx     = (const int*)d_in[7];
    const int*   xtype    = (const int*)d_in[8];
    const int*   imRow    = (const int*)d_in[9];
    const int*   imCol    = (const int*)d_in[10];

    const int NU  = in_sizes[0] / CDIM;
    const int NE  = in_sizes[1] / CDIM;
    const int NN  = NU + NE;
    const int E   = in_sizes[5] / 2;
    const int E2  = in_sizes[7] / 2;
    const int NNZ = in_sizes[4];
    const long nuC = (long)NU * CDIM, neC = (long)NE * CDIM, nnC = (long)NN * CDIM;

    const int BcE = (NE + 1023) >> 10, BcN = (NN + 1023) >> 10, BcU = (NU + 1023) >> 10;

    float* out = (float*)d_out;
    float* outUserRes = out;            // [0 : nuC]
    float* entOut     = out + nuC;      // [nuC : nnC] ping-pong; final hop lands here
    float* outNodeRes = out + nnC;      // [nnC : 2nnC]

    // ---- workspace layout ----
    size_t required = (size_t)(neC + 2 * nuC) * 4          // entA, nodeU_A, nodeU_B
                    + (size_t)NE * 4                        // entNorm
                    + (size_t)(E + E2 + NNZ) * 4 * 2        // stage + bin keys
                    + (size_t)NNZ * 4 * 2                   // stageVal + binVal
                    + (size_t)(3 * MAXB) * 4                // coarse counts
                    + (size_t)(3 * (MAXB + 1)) * 4          // coarse starts
                    + (size_t)(3 * MAXB) * 4                // cursors
                    + (size_t)(NE + NN + NU + 3) * 4;       // rowStart CSR arrays
    if (ws_size < required) {
        long total = 2 * nnC;
        fill_debug<<<(total + 255) / 256, 256, 0, stream>>>(out, total, (float)(ws_size >> 20));
        return;
    }

    char* w = (char*)d_ws;
    float* entA     = (float*)w; w += (size_t)neC * 4;
    float* nodeU_A  = (float*)w; w += (size_t)nuC * 4;
    float* nodeU_B  = (float*)w; w += (size_t)nuC * 4;
    float* entNorm  = (float*)w; w += (size_t)NE * 4;
    int* stageEnt   = (int*)w;   w += (size_t)E * 4;
    int* stageNode  = (int*)w;   w += (size_t)E2 * 4;
    int* stageU     = (int*)w;   w += (size_t)NNZ * 4;
    float* stageUv  = (float*)w; w += (size_t)NNZ * 4;
    int* binEnt     = (int*)w;   w += (size_t)E * 4;
    int* binNode    = (int*)w;   w += (size_t)E2 * 4;
    int* binU       = (int*)w;   w += (size_t)NNZ * 4;
    float* binUv    = (float*)w; w += (size_t)NNZ * 4;
    int* cntC       = (int*)w;   w += (size_t)(3 * MAXB) * 4;
    int* startE     = (int*)w;   w += (size_t)(MAXB + 1) * 4;
    int* startN     = (int*)w;   w += (size_t)(MAXB + 1) * 4;
    int* startU     = (int*)w;   w += (size_t)(MAXB + 1) * 4;
    int* curE       = (int*)w;   w += (size_t)MAXB * 4;
    int* curN       = (int*)w;   w += (size_t)MAXB * 4;
    int* curU       = (int*)w;   w += (size_t)MAXB * 4;
    int* rowSE      = (int*)w;   w += (size_t)(NE + 1) * 4;
    int* rowSN      = (int*)w;   w += (size_t)(NN + 1) * 4;
    int* rowSU      = (int*)w;   w += (size_t)(NU + 1) * 4;

    const int* head = eidx;  const int* tail = eidx + E;
    const int* eh   = xidx;  const int* et   = xidx + E2;

    hipMemsetAsync(cntC, 0, (size_t)(3 * MAXB) * 4, stream);

    long initN4 = (nuC > neC ? nuC : neC) / 4;
    init_kernel<<<(initN4 + 255) / 256, 256, 0, stream>>>(
        (const float4*)user_emb, (const float4*)ent_emb,
        (float4*)outUserRes, (float4*)outNodeRes, nuC / 4, neC / 4);

    // ---- build: hist -> scan -> coarse bin -> per-row subsort (CSR) ----
    hist_coarse<<<256, 256, 0, stream>>>(head,  E,   cntC,            BcE);
    hist_coarse<<<256, 256, 0, stream>>>(eh,    E2,  cntC + MAXB,     BcN);
    hist_coarse<<<256, 256, 0, stream>>>(imRow, NNZ, cntC + 2 * MAXB, BcU);

    scan_small<<<1, 256, 0, stream>>>(cntC,            startE, curE, BcE);
    scan_small<<<1, 256, 0, stream>>>(cntC + MAXB,     startN, curN, BcN);
    scan_small<<<1, 256, 0, stream>>>(cntC + 2 * MAXB, startU, curU, BcU);

    bin_pairs<<<(E  + CHUNK - 1) / CHUNK, 256, 0, stream>>>(head, tail, etype, -1, E,  curE, stageEnt);
    bin_pairs<<<(E2 + CHUNK - 1) / CHUNK, 256, 0, stream>>>(eh,   et,   xtype,  0, E2, curN, stageNode);
    bin_user <<<(NNZ + CHUNK - 1) / CHUNK, 256, 0, stream>>>(imRow, imCol, imVal, NNZ, curU, stageU, stageUv);

    subsort<<<BcE, 256, 0, stream>>>(startE, stageEnt,  nullptr, binEnt,  nullptr, rowSE, BcE, NE, E);
    subsort<<<BcN, 256, 0, stream>>>(startN, stageNode, nullptr, binNode, nullptr, rowSN, BcN, NN, E2);
    subsort<<<BcU, 256, 0, stream>>>(startU, stageU,    stageUv, binU,    binUv,   rowSU, BcU, NU, NNZ);

    // ---- 3 hops (round-5 register gathers) ----
    const float* entCurP  = ent_emb;   float* entNewP  = entOut;
    const float* nodeOldP = user_emb;  float* nodeNewP = nodeU_A;

    for (int hop = 0; hop < 3; ++hop) {
        ent_gather<<<(NE + 3) / 4, 256, 0, stream>>>(
            entCurP, (const float4*)weight, rowSE, binEnt, entNewP, entNorm, NE);
        node_gather<<<(NN + 3) / 4, 256, 0, stream>>>(
            nodeOldP, entCurP, (const float4*)extraW, rowSN, binNode,
            nodeNewP, outNodeRes, NN, NU);
        user_gather<<<(NU + 3) / 4, 256, 0, stream>>>(
            entNewP, entNorm, rowSU, binU, binUv, outUserRes, NU);

        if (hop == 0) {
            entCurP = entOut;  entNewP = entA;
            nodeOldP = nodeU_A; nodeNewP = nodeU_B;
        } else if (hop == 1) {
            entCurP = entA;    entNewP = entOut;
            nodeOldP = nodeU_B; nodeNewP = nodeU_A;
        }
    }
}